// Round 6
// baseline (1772.661 us; speedup 1.0000x reference)
//
#include <hip/hip_runtime.h>
#include <math.h>

// Problem constants: B=32, T=64, N=128, D=64, E=5.  Time chunked: TC=16, 4 chunks.
// Workspace layout (float element offsets; flags occupy first 4 KB as uint32)
constexpr size_t WS_VV  = 1024;
constexpr size_t WS_TOT = 2048;
constexpr size_t WS_RS  = 8192;                  // 262144
constexpr size_t WS_WH  = 270336;                // 3*128*64*64 = 1572864 (Wr|Wu|Wc h-part)
constexpr size_t WS_WX  = 1843200;               // 3*128*65*64 = 1597440
constexpr size_t WS_BF  = 3440640;               // 3*128*64
constexpr size_t WS_H   = 3465216;               // 262144 (recurrent state; MALL-coherent)
constexpr size_t WS_CH  = 3727360;               // 262144 (combH exchange; MALL-coherent)
constexpr size_t WS_CX  = 3989504;               // 128*512*65 = 4259840   [n][b*16+tl][65]
constexpr size_t WS_GXR = 8249344;               // 128*16*32*64 = 4194304 [n][tl][b][o]
constexpr size_t WS_GXU = 12443648;
constexpr size_t WS_CXC = 16637952;
// end = 20832256 floats = 79.5 MiB

__device__ __forceinline__ float sigm(float x){ return 1.f/(1.f+expf(-x)); }

// MALL-coherent (agent-scope relaxed => sc0 sc1, no cache maintenance) 8B ld/st
__device__ __forceinline__ float2 ld2_mall(const float* p){
  union { unsigned long long u; float2 f; } cv;
  cv.u = __hip_atomic_load((const unsigned long long*)p, __ATOMIC_RELAXED,
                           __HIP_MEMORY_SCOPE_AGENT);
  return cv.f;
}
__device__ __forceinline__ void st2_mall(float* p, float a, float b){
  union { unsigned long long u; float2 f; } cv;
  cv.f = make_float2(a, b);
  __hip_atomic_store((unsigned long long*)p, cv.u, __ATOMIC_RELAXED,
                     __HIP_MEMORY_SCOPE_AGENT);
}

// ---------------- vv = relu(vpe@W1+b1)@W2+b2 ----------------
__global__ void k_vv(const float* __restrict__ vpe, const float* __restrict__ W1,
                     const float* __restrict__ b1, const float* __restrict__ W2,
                     const float* __restrict__ b2, float* __restrict__ ws){
  int n = blockIdx.x, tid = threadIdx.x;
  __shared__ float hid[128];
  if (tid < 128){
    float acc = b1[tid];
    for (int k=0;k<768;k++) acc = fmaf(vpe[n*768+k], W1[k*128+tid], acc);
    hid[tid] = fmaxf(acc, 0.f);
  }
  __syncthreads();
  if (tid < 5){
    float acc = b2[tid];
    for (int h=0;h<128;h++) acc = fmaf(hid[h], W2[h*5+tid], acc);
    ws[WS_VV + n*5 + tid] = acc;
  }
}

// ---------------- fold per-node weights: Wn = sum_e vv[n,e]*W[e] ----------------
__global__ void k_fold(const float* __restrict__ Wr, const float* __restrict__ Wu,
                       const float* __restrict__ Wc, const float* __restrict__ br,
                       const float* __restrict__ bu, const float* __restrict__ bc,
                       float* __restrict__ ws){
  int bid = blockIdx.x; int g = bid>>7; int n = bid&127;
  const float* W  = (g==0)?Wr:(g==1)?Wu:Wc;
  const float* bb = (g==0)?br:(g==1)?bu:bc;
  float v[5];
#pragma unroll
  for (int e=0;e<5;e++) v[e] = ws[WS_VV + n*5 + e];
  for (int idx=threadIdx.x; idx<129*64; idx+=256){
    int i = idx>>6, o = idx&63;
    float a = 0.f;
#pragma unroll
    for (int e=0;e<5;e++) a = fmaf(v[e], W[(e*129+i)*64+o], a);
    if (i < 65) ws[WS_WX + (size_t)(g*128+n)*4160 + i*64 + o] = a;
    else        ws[WS_WH + (size_t)(g*128+n)*4096 + (i-65)*64 + o] = a;
  }
  if (threadIdx.x < 64){
    int o = threadIdx.x; float a = 0.f;
#pragma unroll
    for (int e=0;e<5;e++) a = fmaf(v[e], bb[e*64+o], a);
    ws[WS_BF + (g*128+n)*64 + o] = a;
  }
}

// ---------------- tot[b,n] = sum_t mask ----------------
__global__ void k_tot(const float* __restrict__ mask, float* __restrict__ ws){
  int id = blockIdx.x*256 + threadIdx.x;     // 4096
  int b = id>>7, n = id&127;
  float s = 0.f;
  for (int t=0;t<64;t++) s += mask[(b*64+t)*128 + n];
  ws[WS_TOT + b*128 + n] = s;
}

// ---------------- rs = 0.5*tanh(avg/(tot+1)) ----------------
__global__ void k_rs(const float* __restrict__ avg, float* __restrict__ ws){
  int id = blockIdx.x*256 + threadIdx.x;     // 262144
  int b = id>>13, n = id&127;
  float tot = ws[WS_TOT + b*128 + n];
  ws[WS_RS + id] = 0.5f * tanhf(avg[id] / (tot + 1.f));
}

// ---------------- P4a (per chunk): combX = adj @ xtilde, stored [i][b*16+tl][65] ----------------
__global__ __launch_bounds__(256) void p4a(const float* __restrict__ obs,
      const float* __restrict__ mask, const float* __restrict__ adjI,
      const float* __restrict__ rW, const int* __restrict__ lengths,
      float* __restrict__ ws, int c0){
  int rc = blockIdx.x;                 // b*16 + tl
  int b = rc>>4, tl = rc&15, t = c0 + tl;
  if (t >= lengths[b]) return;
  int rt = b*64 + t;
  __shared__ float xt[64*68];
  __shared__ float adjh[128*68];
  __shared__ float rs_l[128], m_l[128];
  int tid = threadIdx.x;
  if (tid < 128){ rs_l[tid] = ws[WS_RS + rt*128 + tid]; m_l[tid] = mask[rt*128 + tid]; }
  __syncthreads();
  int it = tid>>3, ft = tid&7, i0 = it*4, f0 = ft*8;
  float4 aL[4], aH[4]; float a64[4];
#pragma unroll
  for (int ii=0;ii<4;ii++){ aL[ii]=make_float4(0,0,0,0); aH[ii]=make_float4(0,0,0,0); a64[ii]=0.f; }
  for (int half=0; half<2; half++){
    __syncthreads();
    int j0 = half*64;
    for (int idx=tid; idx<4096; idx+=256){
      int jl = idx>>6, f = idx&63;
      xt[jl*68+f] = obs[(size_t)rt*8192 + (j0+jl)*64 + f];
    }
    if (tid < 64) xt[tid*68+64] = rs_l[j0+tid];
    for (int idx=tid; idx<8192; idx+=256){
      int i = idx>>6, jl = idx&63, j = j0+jl;
      float a;
      if (i == j) a = 1.f;
      else {
        int gi = i*128 + j;
        float dd = fabsf(rs_l[i] - rs_l[j]);
        a = adjI[gi] * (1.f - rW[gi]*dd) * m_l[i] * m_l[j];
      }
      adjh[i*68+jl] = a;
    }
    __syncthreads();
    for (int jb=0; jb<16; jb++){
      float4 av[4];
#pragma unroll
      for (int ii=0;ii<4;ii++) av[ii] = *(const float4*)&adjh[(i0+ii)*68 + jb*4];
#pragma unroll
      for (int jj=0;jj<4;jj++){
        int jl = jb*4 + jj;
        float4 xlo = *(const float4*)&xt[jl*68 + f0];
        float4 xhi = *(const float4*)&xt[jl*68 + f0 + 4];
        float xr = xt[jl*68 + 64];
#pragma unroll
        for (int ii=0;ii<4;ii++){
          float a = (jj==0)?av[ii].x:(jj==1)?av[ii].y:(jj==2)?av[ii].z:av[ii].w;
          aL[ii].x = fmaf(a, xlo.x, aL[ii].x); aL[ii].y = fmaf(a, xlo.y, aL[ii].y);
          aL[ii].z = fmaf(a, xlo.z, aL[ii].z); aL[ii].w = fmaf(a, xlo.w, aL[ii].w);
          aH[ii].x = fmaf(a, xhi.x, aH[ii].x); aH[ii].y = fmaf(a, xhi.y, aH[ii].y);
          aH[ii].z = fmaf(a, xhi.z, aH[ii].z); aH[ii].w = fmaf(a, xhi.w, aH[ii].w);
          a64[ii] = fmaf(a, xr, a64[ii]);
        }
      }
    }
  }
#pragma unroll
  for (int ii=0;ii<4;ii++){
    int i = i0 + ii;
    size_t base = WS_CX + (size_t)i*33280 + (size_t)rc*65 + f0;
    ws[base+0]=aL[ii].x; ws[base+1]=aL[ii].y; ws[base+2]=aL[ii].z; ws[base+3]=aL[ii].w;
    ws[base+4]=aH[ii].x; ws[base+5]=aH[ii].y; ws[base+6]=aH[ii].z; ws[base+7]=aH[ii].w;
    if (ft == 0) ws[WS_CX + (size_t)i*33280 + (size_t)rc*65 + 64] = a64[ii];
  }
}

// ---------------- P4b (per chunk): per-node GEMMs for x-part of gates (incl. bias) ----------------
__global__ __launch_bounds__(256) void p4b(const float* __restrict__ obs,
      const int* __restrict__ lengths, float* __restrict__ ws, int c0){
  int bid = blockIdx.x;                 // 1536 = 3 * 128 * 4
  int g = bid >> 9; int r2 = bid & 511; int n = r2 >> 2; int tile = r2 & 3;
  __shared__ float A[128*69];
  __shared__ float Wl[65*64];
  __shared__ float bl[64];
  __shared__ int slen[32];
  int tid = threadIdx.x;
  if (tid < 32) slen[tid] = lengths[tid];
  for (int idx=tid; idx<4160; idx+=256) Wl[idx] = ws[WS_WX + (size_t)(g*128+n)*4160 + idx];
  if (tid < 64) bl[tid] = ws[WS_BF + (g*128+n)*64 + tid];
  if (g < 2){
    const float* src = &ws[WS_CX + (size_t)n*33280 + (size_t)tile*8320];
    for (int idx=tid; idx<8320; idx+=256){
      int r = idx/65, f = idx - r*65;
      A[r*69+f] = src[idx];
    }
  } else {
    for (int idx=tid; idx<8320; idx+=256){
      int r = idx/65, f = idx - r*65;
      int grow = tile*128 + r;              // b*16+tl
      int gb = grow>>4, t = c0 + (grow&15);
      float v = (f < 64) ? obs[(size_t)(gb*64+t)*8192 + n*64 + f]
                         : ws[WS_RS + (gb*64+t)*128 + n];
      A[r*69+f] = v;
    }
  }
  __syncthreads();
  int rt8 = tid>>4, dq = tid&15;
  float4 acc[8];
#pragma unroll
  for (int rr=0;rr<8;rr++) acc[rr] = make_float4(0,0,0,0);
  for (int k=0;k<65;k++){
    float4 w = *(const float4*)&Wl[k*64 + dq*4];
#pragma unroll
    for (int rr=0;rr<8;rr++){
      float a = A[(rt8*8+rr)*69 + k];
      acc[rr].x = fmaf(a,w.x,acc[rr].x); acc[rr].y = fmaf(a,w.y,acc[rr].y);
      acc[rr].z = fmaf(a,w.z,acc[rr].z); acc[rr].w = fmaf(a,w.w,acc[rr].w);
    }
  }
  float4 b4 = *(const float4*)&bl[dq*4];
  float* dst = &ws[(g==0)?WS_GXR:(g==1)?WS_GXU:WS_CXC];
#pragma unroll
  for (int rr=0;rr<8;rr++){
    int grow = tile*128 + rt8*8 + rr;
    int gb = grow>>4, gtl = grow&15;
    if (c0 + gtl < slen[gb]){
      float4 o; o.x=acc[rr].x+b4.x; o.y=acc[rr].y+b4.y; o.z=acc[rr].z+b4.z; o.w=acc[rr].w+b4.w;
      *(float4*)&dst[((size_t)(n*16+gtl)*32 + gb)*64 + dq*4] = o;
    }
  }
}

// ---------------- Recurrent persistent kernel v6 (split roles, per chunk) ----------------
// 512 blocks x 256 threads, all co-resident (2 blocks/CU, 59 KB LDS each).
//  bid<256: A-block (bA=bid>>3, slice sA=bid&7): adj rows + combH rows -> chbuf,
//           flag cfl[sA*32+bA]=t+1.
//  bid>=256: B-block (nB, half hf): node's 48 KB Wr/Wu/Wc in LDS (loaded ONCE per
//           chunk), own h fragments in registers, register-tiled (2 batch x 4 feat)
//           gate GEMMs via transposed [k][bi] LDS tiles, flag hfl[nB*2+hf]=t+1.
// Cross-block data via MALL (sc0 sc1); plain flag stores after vmcnt drain; no atomics.
__global__ __launch_bounds__(256) void krec(const float* __restrict__ mask,
      const int* __restrict__ lengths, const float* __restrict__ adjI,
      const float* __restrict__ rWm, float* __restrict__ out, float* __restrict__ ws,
      int c0){
  unsigned* cfl = (unsigned*)ws;           // [s*32+b]
  unsigned* hfl = ((unsigned*)ws) + 256;   // [n*2+hf]
  const int bid = blockIdx.x, tid = threadIdx.x;
  __shared__ float smem[14848];            // 59392 B
  float* hbuf = &ws[WS_H];
  float* chb  = &ws[WS_CH];

  if (bid < 256){
    // ================= A-role =================
    const int bA = bid>>3, sA = bid&7, ns = sA*16;
    float* hs   = smem;            // 8192
    float* adjT = smem + 8192;     // [j][r] stride 20, 2560
    float* rs_l = smem + 10752;    // 128
    float* m_l  = smem + 10880;    // 128
    const int lenA = lengths[bA];
    const int pr = tid>>4, fq = tid&15;    // tid<128: rows ns+pr*2+{0,1}, feat fq*4
    for (int t=c0; t<c0+16; t++){
      const bool aliveA = (t < lenA);
      if (aliveA){
        if (tid < 128) rs_l[tid] = ws[WS_RS + (size_t)(bA*64+t)*128 + tid];
        else           m_l[tid-128] = mask[(size_t)(bA*64+t)*128 + (tid-128)];
      }
      __syncthreads();                              // rs/m ready
      if (aliveA){
        for (int idx=tid; idx<2048; idx+=256){
          int j = idx&127, r = idx>>7, I = ns+r;
          float a;
          if (I == j) a = 1.f;
          else {
            int gi = I*128 + j;
            float dd = fabsf(rs_l[I] - rs_l[j]);
            a = adjI[gi]*(1.f - rWm[gi]*dd)*m_l[I]*m_l[j];
          }
          adjT[j*20 + r] = a;
        }
        if (t > 0 && tid < 128){
          unsigned tgt = (unsigned)t; int guard = 0;
          while (__hip_atomic_load(&hfl[tid*2 + (bA>>4)], __ATOMIC_RELAXED,
                   __HIP_MEMORY_SCOPE_AGENT) < tgt && ++guard < (1<<20))
            __builtin_amdgcn_s_sleep(1);
        }
      }
      __syncthreads();                              // adjT + poll done
      if (aliveA){
#pragma unroll
        for (int k2=0;k2<16;k2++){
          int p = tid + 256*k2;
          float2 v = ld2_mall(&hbuf[(size_t)bA*8192 + 2*p]);
          *(float2*)&hs[2*p] = v;
        }
      }
      __syncthreads();                              // hs ready
      if (aliveA && tid < 128){
        float4 a0 = make_float4(0,0,0,0), a1 = a0;
#pragma unroll 4
        for (int j=0;j<128;j++){
          float2 aj = *(const float2*)&adjT[j*20 + pr*2];
          float4 h4 = *(const float4*)&hs[j*64 + fq*4];
          a0.x = fmaf(aj.x,h4.x,a0.x); a0.y = fmaf(aj.x,h4.y,a0.y);
          a0.z = fmaf(aj.x,h4.z,a0.z); a0.w = fmaf(aj.x,h4.w,a0.w);
          a1.x = fmaf(aj.y,h4.x,a1.x); a1.y = fmaf(aj.y,h4.y,a1.y);
          a1.z = fmaf(aj.y,h4.z,a1.z); a1.w = fmaf(aj.y,h4.w,a1.w);
        }
        float* cp0 = &chb[((size_t)bA*128 + ns + pr*2)*64 + fq*4];
        st2_mall(cp0,    a0.x, a0.y); st2_mall(cp0+2,  a0.z, a0.w);
        st2_mall(cp0+64, a1.x, a1.y); st2_mall(cp0+66, a1.z, a1.w);
      }
      asm volatile("s_waitcnt vmcnt(0)" ::: "memory");
      __syncthreads();                              // all combH stores drained
      if (tid == 0)
        __hip_atomic_store(&cfl[sA*32 + bA], (unsigned)(t+1), __ATOMIC_RELAXED,
                           __HIP_MEMORY_SCOPE_AGENT);
    }
  } else {
    // ================= B-role =================
    const int nB = (bid-256)>>1, hf = (bid-256)&1, b0 = hf*16;
    float* wR = smem;              // [k*64+f] 4096
    float* wU = smem + 4096;
    float* wC = smem + 8192;
    float* cT = smem + 12288;      // [k][bi] stride 20, 1280
    float* hT = smem + 13568;      // [k][bi] stride 20, 1280
    // one-time: node weights -> LDS (48 KB)
    for (int idx=tid; idx<3072; idx+=256){
      int g = idx>>10, r = idx&1023;
      *(float4*)&smem[g*4096 + r*4] =
        *(const float4*)&ws[WS_WH + (size_t)(g*128+nB)*4096 + (size_t)r*4];
    }
    const int p = tid>>4, fq = tid&15;     // tid<128: batches b0+p*2+{0,1}
    const int bb0 = b0 + ((p&7)*2), bb1 = bb0 + 1;
    const int sl0 = lengths[bb0], sl1 = lengths[bb1];
    float4 h0, h1p;                        // persistent h fragments
    { const float* q0 = &hbuf[((size_t)bb0*128+nB)*64 + fq*4];
      const float* q1 = &hbuf[((size_t)bb1*128+nB)*64 + fq*4];
      float2 a = ld2_mall(q0), b = ld2_mall(q0+2);
      float2 c = ld2_mall(q1), d = ld2_mall(q1+2);
      h0 = make_float4(a.x,a.y,b.x,b.y); h1p = make_float4(c.x,c.y,d.x,d.y); }
    __syncthreads();                        // weights ready
    for (int t=c0; t<c0+16; t++){
      const int tl = t - c0;
      const bool al0 = (t < sl0), al1 = (t < sl1);
      float4 xr0,xr1,xu0,xu1,xc0,xc1; float m0=0.f, m1=0.f;
      if (tid < 128){
        size_t g0 = ((size_t)(nB*16+tl)*32 + bb0)*64 + fq*4;
        size_t g1 = ((size_t)(nB*16+tl)*32 + bb1)*64 + fq*4;
        xr0 = *(const float4*)&ws[WS_GXR + g0]; xr1 = *(const float4*)&ws[WS_GXR + g1];
        xu0 = *(const float4*)&ws[WS_GXU + g0]; xu1 = *(const float4*)&ws[WS_GXU + g1];
        xc0 = *(const float4*)&ws[WS_CXC + g0]; xc1 = *(const float4*)&ws[WS_CXC + g1];
        m0 = mask[(size_t)(bb0*64+t)*128 + nB];
        m1 = mask[(size_t)(bb1*64+t)*128 + nB];
      }
      if (tid < 16){
        unsigned tgt = (unsigned)(t+1); int guard = 0;
        while (__hip_atomic_load(&cfl[(nB>>4)*32 + b0 + tid], __ATOMIC_RELAXED,
                 __HIP_MEMORY_SCOPE_AGENT) < tgt && ++guard < (1<<20))
          __builtin_amdgcn_s_sleep(1);
      }
      __syncthreads();                      // poll done
      { // stage combH rows for 16 batches, transposed -> cT[k][bi]
        int bi = tid>>4, fg = tid&15, f0 = fg*4;
        const float* cp = &chb[((size_t)(b0+bi)*128 + nB)*64 + f0];
        float2 u = ld2_mall(cp), v = ld2_mall(cp+2);
        cT[(f0  )*20 + bi] = u.x; cT[(f0+1)*20 + bi] = u.y;
        cT[(f0+2)*20 + bi] = v.x; cT[(f0+3)*20 + bi] = v.y;
      }
      __syncthreads();                      // cT ready
      float4 uu0, uu1, h1a, h1b;
      const bool ob0 = m0 > 0.f, ob1 = m1 > 0.f;
      if (tid < 128){
        float4 ar0=xr0, ar1=xr1, au0=xu0, au1=xu1;
#pragma unroll 4
        for (int k=0;k<64;k++){
          float2 c2 = *(const float2*)&cT[k*20 + (p&7)*2];
          float4 wr4 = *(const float4*)&wR[k*64 + fq*4];
          float4 wu4 = *(const float4*)&wU[k*64 + fq*4];
          ar0.x = fmaf(c2.x,wr4.x,ar0.x); ar0.y = fmaf(c2.x,wr4.y,ar0.y);
          ar0.z = fmaf(c2.x,wr4.z,ar0.z); ar0.w = fmaf(c2.x,wr4.w,ar0.w);
          ar1.x = fmaf(c2.y,wr4.x,ar1.x); ar1.y = fmaf(c2.y,wr4.y,ar1.y);
          ar1.z = fmaf(c2.y,wr4.z,ar1.z); ar1.w = fmaf(c2.y,wr4.w,ar1.w);
          au0.x = fmaf(c2.x,wu4.x,au0.x); au0.y = fmaf(c2.x,wu4.y,au0.y);
          au0.z = fmaf(c2.x,wu4.z,au0.z); au0.w = fmaf(c2.x,wu4.w,au0.w);
          au1.x = fmaf(c2.y,wu4.x,au1.x); au1.y = fmaf(c2.y,wu4.y,au1.y);
          au1.z = fmaf(c2.y,wu4.z,au1.z); au1.w = fmaf(c2.y,wu4.w,au1.w);
        }
        float4 r0, r1;
        r0.x=sigm(ar0.x); r0.y=sigm(ar0.y); r0.z=sigm(ar0.z); r0.w=sigm(ar0.w);
        r1.x=sigm(ar1.x); r1.y=sigm(ar1.y); r1.z=sigm(ar1.z); r1.w=sigm(ar1.w);
        uu0.x=sigm(au0.x); uu0.y=sigm(au0.y); uu0.z=sigm(au0.z); uu0.w=sigm(au0.w);
        uu1.x=sigm(au1.x); uu1.y=sigm(au1.y); uu1.z=sigm(au1.z); uu1.w=sigm(au1.w);
        bool q0 = al0 && ob0, q1 = al1 && ob1;
        h1a.x = q0 ? r0.x*h0.x : h0.x;  h1a.y = q0 ? r0.y*h0.y : h0.y;
        h1a.z = q0 ? r0.z*h0.z : h0.z;  h1a.w = q0 ? r0.w*h0.w : h0.w;
        h1b.x = q1 ? r1.x*h1p.x : h1p.x; h1b.y = q1 ? r1.y*h1p.y : h1p.y;
        h1b.z = q1 ? r1.z*h1p.z : h1p.z; h1b.w = q1 ? r1.w*h1p.w : h1p.w;
        const float* pa = (const float*)&h1a;
        const float* pb = (const float*)&h1b;
#pragma unroll
        for (int q=0;q<4;q++)
          *(float2*)&hT[(fq*4+q)*20 + (p&7)*2] = make_float2(pa[q], pb[q]);
      }
      __syncthreads();                      // hT ready
      if (tid < 128){
        float4 ac0=xc0, ac1=xc1;
#pragma unroll 4
        for (int k=0;k<64;k++){
          float2 hh = *(const float2*)&hT[k*20 + (p&7)*2];
          float4 wc4 = *(const float4*)&wC[k*64 + fq*4];
          ac0.x = fmaf(hh.x,wc4.x,ac0.x); ac0.y = fmaf(hh.x,wc4.y,ac0.y);
          ac0.z = fmaf(hh.x,wc4.z,ac0.z); ac0.w = fmaf(hh.x,wc4.w,ac0.w);
          ac1.x = fmaf(hh.y,wc4.x,ac1.x); ac1.y = fmaf(hh.y,wc4.y,ac1.y);
          ac1.z = fmaf(hh.y,wc4.z,ac1.z); ac1.w = fmaf(hh.y,wc4.w,ac1.w);
        }
        if (al0){
          float4 cd, h2;
          cd.x=tanhf(ac0.x); cd.y=tanhf(ac0.y); cd.z=tanhf(ac0.z); cd.w=tanhf(ac0.w);
          h2.x = ob0 ? (1.f-uu0.x)*h1a.x + uu0.x*cd.x : h1a.x;
          h2.y = ob0 ? (1.f-uu0.y)*h1a.y + uu0.y*cd.y : h1a.y;
          h2.z = ob0 ? (1.f-uu0.z)*h1a.z + uu0.z*cd.z : h1a.z;
          h2.w = ob0 ? (1.f-uu0.w)*h1a.w + uu0.w*cd.w : h1a.w;
          h0 = h2;
          float* hp = &hbuf[((size_t)bb0*128 + nB)*64 + fq*4];
          st2_mall(hp, h2.x, h2.y); st2_mall(hp+2, h2.z, h2.w);
          if (t == sl0-1) *(float4*)&out[((size_t)bb0*128 + nB)*64 + fq*4] = h2;
        }
        if (al1){
          float4 cd, h2;
          cd.x=tanhf(ac1.x); cd.y=tanhf(ac1.y); cd.z=tanhf(ac1.z); cd.w=tanhf(ac1.w);
          h2.x = ob1 ? (1.f-uu1.x)*h1b.x + uu1.x*cd.x : h1b.x;
          h2.y = ob1 ? (1.f-uu1.y)*h1b.y + uu1.y*cd.y : h1b.y;
          h2.z = ob1 ? (1.f-uu1.z)*h1b.z + uu1.z*cd.z : h1b.z;
          h2.w = ob1 ? (1.f-uu1.w)*h1b.w + uu1.w*cd.w : h1b.w;
          h1p = h2;
          float* hp = &hbuf[((size_t)bb1*128 + nB)*64 + fq*4];
          st2_mall(hp, h2.x, h2.y); st2_mall(hp+2, h2.z, h2.w);
          if (t == sl1-1) *(float4*)&out[((size_t)bb1*128 + nB)*64 + fq*4] = h2;
        }
      }
      asm volatile("s_waitcnt vmcnt(0)" ::: "memory");
      __syncthreads();                      // all h stores drained
      if (tid == 0)
        __hip_atomic_store(&hfl[nB*2 + hf], (unsigned)(t+1), __ATOMIC_RELAXED,
                           __HIP_MEMORY_SCOPE_AGENT);
    }
  }
}

extern "C" void kernel_launch(void* const* d_in, const int* in_sizes, int n_in,
                              void* d_out, int out_size, void* d_ws, size_t ws_size,
                              hipStream_t stream){
  const float* obs  = (const float*)d_in[0];
  const float* maskp= (const float*)d_in[2];
  const int*   lens = (const int*)d_in[5];
  const float* avg  = (const float*)d_in[6];
  const float* vpe  = (const float*)d_in[7];
  const float* rW   = (const float*)d_in[8];
  const float* adjI = (const float*)d_in[9];
  const float* W1   = (const float*)d_in[10];
  const float* b1   = (const float*)d_in[11];
  const float* W2   = (const float*)d_in[12];
  const float* b2   = (const float*)d_in[13];
  const float* Wu   = (const float*)d_in[14];
  const float* bu   = (const float*)d_in[15];
  const float* Wr   = (const float*)d_in[16];
  const float* br   = (const float*)d_in[17];
  const float* Wc   = (const float*)d_in[18];
  const float* bc   = (const float*)d_in[19];
  float* out = (float*)d_out;
  float* ws  = (float*)d_ws;
  hipMemsetAsync(d_ws, 0, 4096, stream);
  hipMemsetAsync((char*)d_ws + WS_H*sizeof(float), 0, 262144*sizeof(float), stream);
  k_vv  <<<128, 256, 0, stream>>>(vpe, W1, b1, W2, b2, ws);
  k_fold<<<384, 256, 0, stream>>>(Wr, Wu, Wc, br, bu, bc, ws);
  k_tot <<<16,  256, 0, stream>>>(maskp, ws);
  k_rs  <<<1024,256, 0, stream>>>(avg, ws);
  for (int c = 0; c < 4; c++){
    int c0 = c*16;
    p4a <<<512, 256, 0, stream>>>(obs, maskp, adjI, rW, lens, ws, c0);
    p4b <<<1536,256, 0, stream>>>(obs, lens, ws, c0);
    krec<<<512, 256, 0, stream>>>(maskp, lens, adjI, rW, out, ws, c0);
  }
}